// Round 9
// baseline (776.978 us; speedup 1.0000x reference)
//
#include <hip/hip_runtime.h>

typedef unsigned short u16t;
typedef unsigned int   u32t;
typedef unsigned long long u64t;

#define NNODE 100000
#define DIN   256
#define HIDN  128
#define DOUTN 64
#define NNZE  1600000
#define EDIR  500000
#define EBI   1000000
#define NBLKS 391            // ceil(NNODE/256)
#define G64   1563           // ceil(NNODE/64)
#define EDIRB 125000         // EDIR/4 edge blocks
#define HISTB 10157          // ceil((NNZE+EBI)/256)

typedef __attribute__((ext_vector_type(8))) short bf16x8;
typedef __attribute__((ext_vector_type(4))) float f32x4;
typedef __attribute__((ext_vector_type(4))) float f4v;

__device__ __forceinline__ u16t f2bf(float f){
  u32t u = __float_as_uint(f);
  u += 0x7FFFu + ((u>>16)&1u);          // round-to-nearest-even
  return (u16t)(u>>16);
}
__device__ __forceinline__ float2 up2(u32t w){
  return make_float2(__uint_as_float(w<<16), __uint_as_float(w&0xFFFF0000u));
}

// ---------------- weight prep: fragment-ready bf16 layouts ----------------
__global__ __launch_bounds__(256) void prep_kernel(const float* __restrict__ Wg,
                                                   const float* __restrict__ Wm,
                                                   const float* __restrict__ Wsg,
                                                   u16t* __restrict__ Wg_pre,
                                                   u16t* __restrict__ Wc_pre){
  int idx = blockIdx.x*256 + threadIdx.x;       // 0..65535
  int e = idx & 7, l = (idx>>3) & 63, f = (idx>>9) & 63, sel = idx>>15;
  int k_in = ((e>>2)<<4) + ((l>>4)<<2) + (e&3);
  if(sel == 0){
    int ks = f>>3, nf = f&7;
    int k = ks*32 + k_in, n = nf*16 + (l&15);
    Wg_pre[idx] = f2bf(Wg[(size_t)k*HIDN + n]);
  } else {
    int ks = f>>4, nf = f&15;
    int k = ks*32 + k_in, c = nf*16 + (l&15);
    int half = c>>7, ci = c&127;
    const float* src = (ci&1) ? Wsg : Wm;
    Wc_pre[idx - 32768] = f2bf(src[(size_t)(half*128 + k)*DOUTN + (ci>>1)]);
  }
}

// ---------------- merged histogram over both edge sets ----------------
__global__ __launch_bounds__(256) void histAB_kernel(const int* __restrict__ gi,
                                                     const int* __restrict__ be,
                                                     u32t* __restrict__ gcnt,
                                                     u32t* __restrict__ bcnt){
  int e = blockIdx.x*256 + threadIdx.x;
  if(e < NNZE) atomicAdd(&gcnt[__builtin_nontemporal_load(&gi[e])], 1u);
  else if(e < NNZE+EBI) atomicAdd(&bcnt[__builtin_nontemporal_load(&be[e-NNZE])], 1u);
}

// ---------------- merged hierarchical scan ----------------
__global__ __launch_bounds__(256) void scanA_kernel(const u32t* __restrict__ gcnt,
                                                    u32t* __restrict__ goffs,
                                                    u32t* __restrict__ gpart,
                                                    const u32t* __restrict__ bcnt,
                                                    u32t* __restrict__ boffs,
                                                    u32t* __restrict__ bpart){
  __shared__ u32t sh[256];
  int b = blockIdx.x;
  const u32t* cnt; u32t *offs, *part; int blk;
  if(b < NBLKS){ cnt=gcnt; offs=goffs; part=gpart; blk=b; }
  else         { cnt=bcnt; offs=boffs; part=bpart; blk=b-NBLKS; }
  int t = threadIdx.x, idx = blk*256 + t;
  u32t v = (idx < NNODE) ? cnt[idx] : 0u;
  sh[t] = v; __syncthreads();
  #pragma unroll
  for(int off=1; off<256; off<<=1){
    u32t x = (t>=off) ? sh[t-off] : 0u;
    __syncthreads();
    sh[t] += x;
    __syncthreads();
  }
  if(idx < NNODE) offs[idx] = sh[t] - v;
  if(t == 255) part[blk] = sh[255];
}
__global__ __launch_bounds__(512) void scanB_kernel(u32t* __restrict__ gpart,
                                                    u32t* __restrict__ bpart){
  __shared__ u32t sh[512];
  u32t* part = (blockIdx.x == 0) ? gpart : bpart;
  int t = threadIdx.x;
  u32t v = (t < NBLKS) ? part[t] : 0u;
  sh[t] = v; __syncthreads();
  #pragma unroll
  for(int off=1; off<512; off<<=1){
    u32t x = (t>=off) ? sh[t-off] : 0u;
    __syncthreads();
    sh[t] += x;
    __syncthreads();
  }
  if(t < NBLKS) part[t] = sh[t] - v;
  if(t == 511) part[NBLKS] = sh[511];
}
__global__ __launch_bounds__(256) void scanC_kernel(u32t* __restrict__ goffs,
                                                    u32t* __restrict__ gcur,
                                                    const u32t* __restrict__ gpart,
                                                    u32t* __restrict__ boffs,
                                                    u32t* __restrict__ bcur,
                                                    const u32t* __restrict__ bpart){
  int b = blockIdx.x;
  u32t *offs, *cur; const u32t* part; int blk;
  if(b < NBLKS){ offs=goffs; cur=gcur; part=gpart; blk=b; }
  else         { offs=boffs; cur=bcur; part=bpart; blk=b-NBLKS; }
  int idx = blk*256 + threadIdx.x;
  if(idx < NNODE){
    u32t o = offs[idx] + part[blk];
    offs[idx] = o; cur[idx] = o;
  }
  if(idx == 0) offs[NNODE] = part[NBLKS];
}

// ---------------- merged bucket fill ----------------
__global__ __launch_bounds__(256) void bucketAB_kernel(const int* __restrict__ gi,
                                                       const float* __restrict__ gv,
                                                       const int* __restrict__ be,
                                                       const float* __restrict__ bv,
                                                       u32t* __restrict__ gcur,
                                                       uint2* __restrict__ gbuck,
                                                       u32t* __restrict__ bcur,
                                                       uint2* __restrict__ bbuck){
  int e = blockIdx.x*256 + threadIdx.x;
  if(e < NNZE){
    int key = __builtin_nontemporal_load(&gi[e]);
    u32t pay = (u32t)__builtin_nontemporal_load(&gi[NNZE+e]);
    float v  = __builtin_nontemporal_load(&gv[e]);
    u32t pos = atomicAdd(&gcur[key], 1u);
    gbuck[pos] = make_uint2(pay, __float_as_uint(v));
  } else if(e < NNZE+EBI){
    int e2 = e - NNZE;
    int key = __builtin_nontemporal_load(&be[e2]);
    u32t pay = (u32t)__builtin_nontemporal_load(&be[EBI+e2]);
    float v  = __builtin_nontemporal_load(&bv[e2]);
    u32t pos = atomicAdd(&bcur[key], 1u);
    bbuck[pos] = make_uint2(pay, __float_as_uint(v));
  }
}

// ---------------- GEMM1 (MFMA): xw[N][128] = X[N][256] @ Wg, bf16 out ----------------
__global__ __launch_bounds__(256) void gemm1_kernel(const float* __restrict__ X,
                                                    const u16t* __restrict__ Wg_pre,
                                                    u16t* __restrict__ xwb){
  __shared__ __align__(16) u16t Xs[64*256];   // 32 KB, 8B-granule XOR-swizzled
  const int t = threadIdx.x, l = t & 63, w = t >> 6;
  const int row0 = blockIdx.x * 64;
  for(int i=0;i<16;i++){
    int m = w*16 + i;
    int mg = min(row0 + m, NNODE-1);
    f4v f = __builtin_nontemporal_load((const f4v*)&X[(size_t)mg*DIN + l*4]);
    u32t lo = (u32t)f2bf(f[0]) | ((u32t)f2bf(f[1])<<16);
    u32t hi = (u32t)f2bf(f[2]) | ((u32t)f2bf(f[3])<<16);
    u32t* p = (u32t*)&Xs[m*256 + ((l ^ (m&15))<<2)];
    p[0] = lo; p[1] = hi;
  }
  __syncthreads();
  f32x4 acc[8];
  #pragma unroll
  for(int nf=0;nf<8;nf++) acc[nf] = (f32x4)(0.f);
  const int lm = l & 15, l4 = l >> 4;
  const int mrow = w*16 + lm;
  #pragma unroll 1
  for(int ks=0; ks<8; ks++){
    int kg = ks*8 + l4;
    union { uint2 u2[2]; bf16x8 v; } a;
    a.u2[0] = *(const uint2*)&Xs[mrow*256 + ((kg     ^ lm)<<2)];
    a.u2[1] = *(const uint2*)&Xs[mrow*256 + (((kg+4) ^ lm)<<2)];
    #pragma unroll
    for(int nf=0;nf<8;nf++){
      union { uint4 u4; bf16x8 v; } b;
      b.u4 = *(const uint4*)&Wg_pre[(size_t)((ks*8+nf)*64 + l)*8];
      acc[nf] = __builtin_amdgcn_mfma_f32_16x16x32_bf16(a.v, b.v, acc[nf], 0, 0, 0);
    }
  }
  #pragma unroll
  for(int r=0;r<4;r++){
    int gr = row0 + w*16 + l4*4 + r;
    if(gr < NNODE){
      #pragma unroll
      for(int nf=0;nf<8;nf++)
        xwb[(size_t)gr*HIDN + nf*16 + lm] = f2bf(acc[nf][r]);
    }
  }
}

// ---------------- GCN gather-reduce ----------------
__global__ __launch_bounds__(256) void gcn_gather_kernel(const u16t* __restrict__ xwb,
                                                         const uint2* __restrict__ bucket,
                                                         const u32t* __restrict__ offs,
                                                         u32t* __restrict__ hiddenw){
  int n = blockIdx.x*4 + (threadIdx.x>>6);
  if(n >= NNODE) return;
  int l = threadIdx.x & 63;
  u32t start = offs[n], end = offs[n+1];
  const u32t* xww = (const u32t*)xwb;
  float acc0 = 0.f, acc1 = 0.f;
  for(u32t b = start; b < end; b += 64){
    int nb = min(64, (int)(end - b));
    uint2 ent = make_uint2(0u, 0u);
    if(l < nb){
      u64t ev = __builtin_nontemporal_load((const u64t*)&bucket[b + l]);
      ent = make_uint2((u32t)ev, (u32t)(ev>>32));
    }
    for(int j=0;j<nb;j++){
      u32t s  = __shfl(ent.x, j);
      float v = __uint_as_float(__shfl((int)ent.y, j));
      float2 x = up2(xww[(size_t)s*64 + l]);
      acc0 += v*x.x;
      acc1 += v*x.y;
    }
  }
  hiddenw[(size_t)n*64 + l] = (u32t)f2bf(acc0) | ((u32t)f2bf(acc1)<<16);
}

// ---------------- GEMM2 (MFMA): SRCw (in-place over hiddenw) + DSTw ----------------
__global__ __launch_bounds__(256) void gemm2_kernel(u32t* __restrict__ hiddenw,
                                                    const u16t* __restrict__ Wc_pre,
                                                    u16t* __restrict__ DSTw){
  __shared__ __align__(16) u16t Hs[64*128];   // 16 KB
  const int t = threadIdx.x, l = t & 63, w = t >> 6;
  const int row0 = blockIdx.x * 64;
  for(int i=0;i<16;i++){
    int m = w*16 + i;
    int mg = min(row0 + m, NNODE-1);
    u32t v = hiddenw[(size_t)mg*64 + l];
    *(u32t*)&Hs[m*128 + (((l>>1) ^ (m&15))<<2) + ((l&1)<<1)] = v;
  }
  __syncthreads();
  f32x4 acc[16];
  #pragma unroll
  for(int nf=0;nf<16;nf++) acc[nf] = (f32x4)(0.f);
  const int lm = l & 15, l4 = l >> 4;
  const int mrow = w*16 + lm;
  #pragma unroll 1
  for(int ks=0; ks<4; ks++){
    int kg = ks*8 + l4;
    union { uint2 u2[2]; bf16x8 v; } a;
    a.u2[0] = *(const uint2*)&Hs[mrow*128 + ((kg     ^ lm)<<2)];
    a.u2[1] = *(const uint2*)&Hs[mrow*128 + (((kg+4) ^ lm)<<2)];
    #pragma unroll
    for(int nf=0;nf<16;nf++){
      union { uint4 u4; bf16x8 v; } b;
      b.u4 = *(const uint4*)&Wc_pre[(size_t)((ks*16+nf)*64 + l)*8];
      acc[nf] = __builtin_amdgcn_mfma_f32_16x16x32_bf16(a.v, b.v, acc[nf], 0, 0, 0);
    }
  }
  u16t* SRCw = (u16t*)hiddenw;   // in-place: this block's rows were staged above
  #pragma unroll
  for(int r=0;r<4;r++){
    int gr = row0 + w*16 + l4*4 + r;
    if(gr < NNODE){
      #pragma unroll
      for(int nf=0;nf<8;nf++)
        SRCw[(size_t)gr*HIDN + nf*16 + lm] = f2bf(acc[nf][r]);
      #pragma unroll
      for(int nf=8;nf<16;nf++)
        DSTw[(size_t)gr*HIDN + (nf-8)*16 + lm] = f2bf(acc[nf][r]);
    }
  }
}

// ---------------- fused edge heads + bi gather/finalize ----------------
// every 6th block is a bi block (5:1 edge:bi interleave)
__global__ __launch_bounds__(256) void edgebi_kernel(const u16t* __restrict__ SRCb,
                                                     const u16t* __restrict__ DSTb,
                                                     const int*  __restrict__ ed,
                                                     const float* __restrict__ nin,
                                                     const float* __restrict__ nout,
                                                     float* __restrict__ ein,
                                                     float* __restrict__ eout,
                                                     const uint2* __restrict__ bbuck,
                                                     const u32t* __restrict__ boffs,
                                                     const float* __restrict__ nn,
                                                     float* __restrict__ outp){
  const int bid = blockIdx.x;
  const int l = threadIdx.x & 63;
  const int k = bid/6, r = bid%6;
  const u32t* Sw = (const u32t*)SRCb;
  const u32t* Dw = (const u32t*)DSTb;
  if(r != 0){
    int e = (k*5 + r - 1)*4 + (threadIdx.x>>6);
    int s = ed[e], d = ed[EDIR+e];
    float2 Ss = up2(Sw[(size_t)s*64 + l]);
    float2 Ds = up2(Dw[(size_t)s*64 + l]);
    float2 Sd = up2(Sw[(size_t)d*64 + l]);
    float2 Dd = up2(Dw[(size_t)d*64 + l]);
    size_t o = (size_t)e*DOUTN + l;
    float ni = __builtin_nontemporal_load(&nin[o]);
    float no = __builtin_nontemporal_load(&nout[o]);
    float miu_in  = Ss.x + Dd.x, ls_in  = Ss.y + Dd.y;
    float miu_out = Sd.x + Ds.x, ls_out = Sd.y + Ds.y;
    __builtin_nontemporal_store(ni * __expf(ls_in)  + miu_in,  &ein[o]);
    __builtin_nontemporal_store(no * __expf(ls_out) + miu_out, &eout[o]);
  } else {
    int n = k*4 + (threadIdx.x>>6);
    if(n >= NNODE) return;
    float2 S = up2(Sw[(size_t)n*64 + l]);
    u32t start = boffs[n], end = boffs[n+1];
    float nmiu = 0.f, nvar = 0.f;
    for(u32t b = start; b < end; b += 64){
      int nb = min(64, (int)(end - b));
      uint2 ent = make_uint2(0u, 0u);
      if(l < nb){
        u64t ev = __builtin_nontemporal_load((const u64t*)&bbuck[b + l]);
        ent = make_uint2((u32t)ev, (u32t)(ev>>32));
      }
      for(int j=0;j<nb;j++){
        u32t b1 = __shfl(ent.x, j);
        float v = __uint_as_float(__shfl((int)ent.y, j));
        float2 D = up2(Dw[(size_t)b1*64 + l]);
        nmiu += v*(S.x + D.x);
        nvar += v*v*__expf(S.y + D.y);
      }
    }
    size_t o = (size_t)n*DOUTN + l;
    float nd = __builtin_nontemporal_load(&nn[o]);
    __builtin_nontemporal_store(nd*sqrtf(nvar) + nmiu, &outp[o]);  // exp(0.5*log v)==sqrt(v)
  }
}

extern "C" void kernel_launch(void* const* d_in, const int* in_sizes, int n_in,
                              void* d_out, int out_size, void* d_ws, size_t ws_size,
                              hipStream_t stream){
  const float* X    = (const float*)d_in[0];
  const float* Wg   = (const float*)d_in[1];
  const float* Wm   = (const float*)d_in[2];
  const float* Wsg  = (const float*)d_in[3];
  const float* gv   = (const float*)d_in[4];
  const float* bv   = (const float*)d_in[5];
  const float* nin  = (const float*)d_in[6];
  const float* nout = (const float*)d_in[7];
  const float* nnod = (const float*)d_in[8];
  const int*  gi   = (const int*)d_in[9];
  const int*  ed   = (const int*)d_in[10];
  const int*  be   = (const int*)d_in[11];

  // workspace (76.8 MB):
  //  [0,12.8M)        gbuck uint2          -> phase2: DSTw bf16 [0,25.6M)
  //  [12.8M,38.4M)    xwb bf16             -> (tail of DSTw)
  //  [38.4M,40.0M)    metadata: goffs | gcur | bcur | gpart | bpart | boffs
  //  [40.0M,48.0M)    bbuck uint2 (lives until edgebi)
  //  [51.2M,76.8M)    hiddenw u32-packed bf16 -> in-place SRCw bf16 after gemm2
  char* ws = (char*)d_ws;
  uint2* gbuck   = (uint2*)ws;
  u16t*  xwb     = (u16t*)(ws + 12800000);
  u32t*  goffs   = (u32t*)(ws + 38400000);
  u32t*  gcur    = (u32t*)(ws + 38800008);
  u32t*  bcur    = (u32t*)(ws + 39200008);
  u32t*  gpart   = (u32t*)(ws + 39600008);
  u32t*  bpart   = (u32t*)(ws + 39601584);
  u32t*  boffs   = (u32t*)(ws + 39603160);
  uint2* bbuck   = (uint2*)(ws + 40003168);
  u32t*  hiddenw = (u32t*)(ws + 51200000);
  u16t*  SRCw    = (u16t*)hiddenw;
  u16t*  DSTw    = (u16t*)ws;

  float* out  = (float*)d_out;
  float* ein  = out + (size_t)NNODE*DOUTN;
  float* eout = ein + (size_t)EDIR*DOUTN;
  // weight-prep arrays in tail of d_out's node region; dead before edgebi overwrites
  u16t* Wg_pre = (u16t*)((char*)d_out + 25600000 - 131072);
  u16t* Wc_pre = Wg_pre + 32768;

  hipMemsetAsync(gcur, 0, 800000, stream);                      // gcur + bcur
  histAB_kernel   <<<HISTB,   256, 0, stream>>>(gi, be, gcur, bcur);
  scanA_kernel    <<<2*NBLKS, 256, 0, stream>>>(gcur, goffs, gpart, bcur, boffs, bpart);
  scanB_kernel    <<<2,       512, 0, stream>>>(gpart, bpart);
  scanC_kernel    <<<2*NBLKS, 256, 0, stream>>>(goffs, gcur, gpart, boffs, bcur, bpart);
  bucketAB_kernel <<<HISTB,   256, 0, stream>>>(gi, gv, be, bv, gcur, gbuck, bcur, bbuck);
  prep_kernel     <<<256,     256, 0, stream>>>(Wg, Wm, Wsg, Wg_pre, Wc_pre);
  gemm1_kernel    <<<G64,     256, 0, stream>>>(X, Wg_pre, xwb);
  gcn_gather_kernel<<<NNODE/4,256, 0, stream>>>(xwb, gbuck, goffs, hiddenw);
  gemm2_kernel    <<<G64,     256, 0, stream>>>(hiddenw, Wc_pre, DSTw);
  edgebi_kernel   <<<EDIRB+NNODE/4, 256, 0, stream>>>(SRCw, DSTw, ed, nin, nout,
                                                      ein, eout, bbuck, boffs, nnod, out);
}

// Round 10
// 622.381 us; speedup vs baseline: 1.2484x; 1.2484x over previous
//
#include <hip/hip_runtime.h>

typedef unsigned short u16t;
typedef unsigned int   u32t;
typedef unsigned long long u64t;

#define NNODE 100000
#define DIN   256
#define HIDN  128
#define DOUTN 64
#define NNZE  1600000
#define EDIR  500000
#define EBI   1000000
#define NBLKS 391            // ceil(NNODE/256)
#define G64   1563           // ceil(NNODE/64)
#define HISTB 10157          // ceil((NNZE+EBI)/256)

typedef __attribute__((ext_vector_type(8))) short bf16x8;
typedef __attribute__((ext_vector_type(4))) float f32x4;
typedef __attribute__((ext_vector_type(4))) float f4v;

__device__ __forceinline__ u16t f2bf(float f){
  u32t u = __float_as_uint(f);
  u += 0x7FFFu + ((u>>16)&1u);          // round-to-nearest-even
  return (u16t)(u>>16);
}
__device__ __forceinline__ float2 up2(u32t w){
  return make_float2(__uint_as_float(w<<16), __uint_as_float(w&0xFFFF0000u));
}

// ---------------- weight prep: fragment-ready bf16 layouts ----------------
__global__ __launch_bounds__(256) void prep_kernel(const float* __restrict__ Wg,
                                                   const float* __restrict__ Wm,
                                                   const float* __restrict__ Wsg,
                                                   u16t* __restrict__ Wg_pre,
                                                   u16t* __restrict__ Wc_pre){
  int idx = blockIdx.x*256 + threadIdx.x;       // 0..65535
  int e = idx & 7, l = (idx>>3) & 63, f = (idx>>9) & 63, sel = idx>>15;
  int k_in = ((e>>2)<<4) + ((l>>4)<<2) + (e&3);
  if(sel == 0){
    int ks = f>>3, nf = f&7;
    int k = ks*32 + k_in, n = nf*16 + (l&15);
    Wg_pre[idx] = f2bf(Wg[(size_t)k*HIDN + n]);
  } else {
    int ks = f>>4, nf = f&15;
    int k = ks*32 + k_in, c = nf*16 + (l&15);
    int half = c>>7, ci = c&127;
    const float* src = (ci&1) ? Wsg : Wm;
    Wc_pre[idx - 32768] = f2bf(src[(size_t)(half*128 + k)*DOUTN + (ci>>1)]);
  }
}

// ---------------- merged histogram over both edge sets ----------------
__global__ __launch_bounds__(256) void histAB_kernel(const int* __restrict__ gi,
                                                     const int* __restrict__ be,
                                                     u32t* __restrict__ gcnt,
                                                     u32t* __restrict__ bcnt){
  int e = blockIdx.x*256 + threadIdx.x;
  if(e < NNZE) atomicAdd(&gcnt[__builtin_nontemporal_load(&gi[e])], 1u);
  else if(e < NNZE+EBI) atomicAdd(&bcnt[__builtin_nontemporal_load(&be[e-NNZE])], 1u);
}

// ---------------- merged hierarchical scan ----------------
__global__ __launch_bounds__(256) void scanA_kernel(const u32t* __restrict__ gcnt,
                                                    u32t* __restrict__ goffs,
                                                    u32t* __restrict__ gpart,
                                                    const u32t* __restrict__ bcnt,
                                                    u32t* __restrict__ boffs,
                                                    u32t* __restrict__ bpart){
  __shared__ u32t sh[256];
  int b = blockIdx.x;
  const u32t* cnt; u32t *offs, *part; int blk;
  if(b < NBLKS){ cnt=gcnt; offs=goffs; part=gpart; blk=b; }
  else         { cnt=bcnt; offs=boffs; part=bpart; blk=b-NBLKS; }
  int t = threadIdx.x, idx = blk*256 + t;
  u32t v = (idx < NNODE) ? cnt[idx] : 0u;
  sh[t] = v; __syncthreads();
  #pragma unroll
  for(int off=1; off<256; off<<=1){
    u32t x = (t>=off) ? sh[t-off] : 0u;
    __syncthreads();
    sh[t] += x;
    __syncthreads();
  }
  if(idx < NNODE) offs[idx] = sh[t] - v;
  if(t == 255) part[blk] = sh[255];
}
__global__ __launch_bounds__(512) void scanB_kernel(u32t* __restrict__ gpart,
                                                    u32t* __restrict__ bpart){
  __shared__ u32t sh[512];
  u32t* part = (blockIdx.x == 0) ? gpart : bpart;
  int t = threadIdx.x;
  u32t v = (t < NBLKS) ? part[t] : 0u;
  sh[t] = v; __syncthreads();
  #pragma unroll
  for(int off=1; off<512; off<<=1){
    u32t x = (t>=off) ? sh[t-off] : 0u;
    __syncthreads();
    sh[t] += x;
    __syncthreads();
  }
  if(t < NBLKS) part[t] = sh[t] - v;
  if(t == 511) part[NBLKS] = sh[511];
}
__global__ __launch_bounds__(256) void scanC_kernel(u32t* __restrict__ goffs,
                                                    u32t* __restrict__ gcur,
                                                    const u32t* __restrict__ gpart,
                                                    u32t* __restrict__ boffs,
                                                    u32t* __restrict__ bcur,
                                                    const u32t* __restrict__ bpart){
  int b = blockIdx.x;
  u32t *offs, *cur; const u32t* part; int blk;
  if(b < NBLKS){ offs=goffs; cur=gcur; part=gpart; blk=b; }
  else         { offs=boffs; cur=bcur; part=bpart; blk=b-NBLKS; }
  int idx = blk*256 + threadIdx.x;
  if(idx < NNODE){
    u32t o = offs[idx] + part[blk];
    offs[idx] = o; cur[idx] = o;
  }
  if(idx == 0) offs[NNODE] = part[NBLKS];
}

// ---------------- merged bucket fill ----------------
__global__ __launch_bounds__(256) void bucketAB_kernel(const int* __restrict__ gi,
                                                       const float* __restrict__ gv,
                                                       const int* __restrict__ be,
                                                       const float* __restrict__ bv,
                                                       u32t* __restrict__ gcur,
                                                       uint2* __restrict__ gbuck,
                                                       u32t* __restrict__ bcur,
                                                       uint2* __restrict__ bbuck){
  int e = blockIdx.x*256 + threadIdx.x;
  if(e < NNZE){
    int key = __builtin_nontemporal_load(&gi[e]);
    u32t pay = (u32t)__builtin_nontemporal_load(&gi[NNZE+e]);
    float v  = __builtin_nontemporal_load(&gv[e]);
    u32t pos = atomicAdd(&gcur[key], 1u);
    gbuck[pos] = make_uint2(pay, __float_as_uint(v));
  } else if(e < NNZE+EBI){
    int e2 = e - NNZE;
    int key = __builtin_nontemporal_load(&be[e2]);
    u32t pay = (u32t)__builtin_nontemporal_load(&be[EBI+e2]);
    float v  = __builtin_nontemporal_load(&bv[e2]);
    u32t pos = atomicAdd(&bcur[key], 1u);
    bbuck[pos] = make_uint2(pay, __float_as_uint(v));
  }
}

// ---------------- GEMM1 (MFMA): xw[N][128] = X[N][256] @ Wg, bf16 out ----------------
__global__ __launch_bounds__(256) void gemm1_kernel(const float* __restrict__ X,
                                                    const u16t* __restrict__ Wg_pre,
                                                    u16t* __restrict__ xwb){
  __shared__ __align__(16) u16t Xs[64*256];   // 32 KB, 8B-granule XOR-swizzled
  const int t = threadIdx.x, l = t & 63, w = t >> 6;
  const int row0 = blockIdx.x * 64;
  for(int i=0;i<16;i++){
    int m = w*16 + i;
    int mg = min(row0 + m, NNODE-1);
    f4v f = __builtin_nontemporal_load((const f4v*)&X[(size_t)mg*DIN + l*4]);
    u32t lo = (u32t)f2bf(f[0]) | ((u32t)f2bf(f[1])<<16);
    u32t hi = (u32t)f2bf(f[2]) | ((u32t)f2bf(f[3])<<16);
    u32t* p = (u32t*)&Xs[m*256 + ((l ^ (m&15))<<2)];
    p[0] = lo; p[1] = hi;
  }
  __syncthreads();
  f32x4 acc[8];
  #pragma unroll
  for(int nf=0;nf<8;nf++) acc[nf] = (f32x4)(0.f);
  const int lm = l & 15, l4 = l >> 4;
  const int mrow = w*16 + lm;
  #pragma unroll 1
  for(int ks=0; ks<8; ks++){
    int kg = ks*8 + l4;
    union { uint2 u2[2]; bf16x8 v; } a;
    a.u2[0] = *(const uint2*)&Xs[mrow*256 + ((kg     ^ lm)<<2)];
    a.u2[1] = *(const uint2*)&Xs[mrow*256 + (((kg+4) ^ lm)<<2)];
    #pragma unroll
    for(int nf=0;nf<8;nf++){
      union { uint4 u4; bf16x8 v; } b;
      b.u4 = *(const uint4*)&Wg_pre[(size_t)((ks*8+nf)*64 + l)*8];
      acc[nf] = __builtin_amdgcn_mfma_f32_16x16x32_bf16(a.v, b.v, acc[nf], 0, 0, 0);
    }
  }
  #pragma unroll
  for(int r=0;r<4;r++){
    int gr = row0 + w*16 + l4*4 + r;
    if(gr < NNODE){
      #pragma unroll
      for(int nf=0;nf<8;nf++)
        xwb[(size_t)gr*HIDN + nf*16 + lm] = f2bf(acc[nf][r]);
    }
  }
}

// ---------------- GCN gather-reduce (4x unrolled gathers) ----------------
__global__ __launch_bounds__(256) void gcn_gather_kernel(const u16t* __restrict__ xwb,
                                                         const uint2* __restrict__ bucket,
                                                         const u32t* __restrict__ offs,
                                                         u32t* __restrict__ hiddenw){
  int n = blockIdx.x*4 + (threadIdx.x>>6);
  if(n >= NNODE) return;
  int l = threadIdx.x & 63;
  u32t start = offs[n], end = offs[n+1];
  const u32t* xww = (const u32t*)xwb;
  float acc0 = 0.f, acc1 = 0.f;
  for(u32t b = start; b < end; b += 64){
    int nb = min(64, (int)(end - b));
    uint2 ent = make_uint2(0u, 0u);               // lanes >= nb: s=0, v=0 (harmless)
    if(l < nb){
      u64t ev = __builtin_nontemporal_load((const u64t*)&bucket[b + l]);
      ent = make_uint2((u32t)ev, (u32t)(ev>>32));
    }
    int nbr = (nb + 3) & ~3;
    for(int j=0;j<nbr;j+=4){
      float2 xs[4]; float vs[4];
      #pragma unroll
      for(int q=0;q<4;q++){
        u32t s = __shfl(ent.x, j+q);
        vs[q]  = __uint_as_float(__shfl((int)ent.y, j+q));
        xs[q]  = up2(xww[(size_t)s*64 + l]);
      }
      #pragma unroll
      for(int q=0;q<4;q++){
        acc0 += vs[q]*xs[q].x;
        acc1 += vs[q]*xs[q].y;
      }
    }
  }
  hiddenw[(size_t)n*64 + l] = (u32t)f2bf(acc0) | ((u32t)f2bf(acc1)<<16);
}

// ---------------- GEMM2 (MFMA): SRCw (in-place over hiddenw) + DSTw ----------------
__global__ __launch_bounds__(256) void gemm2_kernel(u32t* __restrict__ hiddenw,
                                                    const u16t* __restrict__ Wc_pre,
                                                    u16t* __restrict__ DSTw){
  __shared__ __align__(16) u16t Hs[64*128];   // 16 KB
  const int t = threadIdx.x, l = t & 63, w = t >> 6;
  const int row0 = blockIdx.x * 64;
  for(int i=0;i<16;i++){
    int m = w*16 + i;
    int mg = min(row0 + m, NNODE-1);
    u32t v = hiddenw[(size_t)mg*64 + l];
    *(u32t*)&Hs[m*128 + (((l>>1) ^ (m&15))<<2) + ((l&1)<<1)] = v;
  }
  __syncthreads();
  f32x4 acc[16];
  #pragma unroll
  for(int nf=0;nf<16;nf++) acc[nf] = (f32x4)(0.f);
  const int lm = l & 15, l4 = l >> 4;
  const int mrow = w*16 + lm;
  #pragma unroll 1
  for(int ks=0; ks<4; ks++){
    int kg = ks*8 + l4;
    union { uint2 u2[2]; bf16x8 v; } a;
    a.u2[0] = *(const uint2*)&Hs[mrow*128 + ((kg     ^ lm)<<2)];
    a.u2[1] = *(const uint2*)&Hs[mrow*128 + (((kg+4) ^ lm)<<2)];
    #pragma unroll
    for(int nf=0;nf<16;nf++){
      union { uint4 u4; bf16x8 v; } b;
      b.u4 = *(const uint4*)&Wc_pre[(size_t)((ks*16+nf)*64 + l)*8];
      acc[nf] = __builtin_amdgcn_mfma_f32_16x16x32_bf16(a.v, b.v, acc[nf], 0, 0, 0);
    }
  }
  u16t* SRCw = (u16t*)hiddenw;   // in-place: this block's rows were staged above
  #pragma unroll
  for(int r=0;r<4;r++){
    int gr = row0 + w*16 + l4*4 + r;
    if(gr < NNODE){
      #pragma unroll
      for(int nf=0;nf<8;nf++)
        SRCw[(size_t)gr*HIDN + nf*16 + lm] = f2bf(acc[nf][r]);
      #pragma unroll
      for(int nf=8;nf<16;nf++)
        DSTw[(size_t)gr*HIDN + (nf-8)*16 + lm] = f2bf(acc[nf][r]);
    }
  }
}

// ---------------- directed-edge heads: 4 edges per wave (16 gathers in flight) ----------------
__global__ __launch_bounds__(256) void edge_kernel(const u16t* __restrict__ SRCb,
                                                   const u16t* __restrict__ DSTb,
                                                   const int*  __restrict__ ed,
                                                   const float* __restrict__ nin,
                                                   const float* __restrict__ nout,
                                                   float* __restrict__ ein,
                                                   float* __restrict__ eout){
  const int e0 = (blockIdx.x*4 + (threadIdx.x>>6))*4;
  const int l = threadIdx.x & 63;
  const u32t* Sw = (const u32t*)SRCb;
  const u32t* Dw = (const u32t*)DSTb;
  int s[4], d[4];
  #pragma unroll
  for(int q=0;q<4;q++){ s[q] = ed[e0+q]; d[q] = ed[EDIR+e0+q]; }
  float2 Ss[4], Ds[4], Sd[4], Dd[4];
  float ni[4], no[4];
  #pragma unroll
  for(int q=0;q<4;q++){
    Ss[q] = up2(Sw[(size_t)s[q]*64 + l]);
    Ds[q] = up2(Dw[(size_t)s[q]*64 + l]);
    Sd[q] = up2(Sw[(size_t)d[q]*64 + l]);
    Dd[q] = up2(Dw[(size_t)d[q]*64 + l]);
    ni[q] = __builtin_nontemporal_load(&nin[(size_t)(e0+q)*DOUTN + l]);
    no[q] = __builtin_nontemporal_load(&nout[(size_t)(e0+q)*DOUTN + l]);
  }
  #pragma unroll
  for(int q=0;q<4;q++){
    size_t o = (size_t)(e0+q)*DOUTN + l;
    float miu_in  = Ss[q].x + Dd[q].x, ls_in  = Ss[q].y + Dd[q].y;
    float miu_out = Sd[q].x + Ds[q].x, ls_out = Sd[q].y + Ds[q].y;
    __builtin_nontemporal_store(ni[q] * __expf(ls_in)  + miu_in,  &ein[o]);
    __builtin_nontemporal_store(no[q] * __expf(ls_out) + miu_out, &eout[o]);
  }
}

// ---------------- bi gather-reduce + finalize (4x unrolled gathers) ----------------
__global__ __launch_bounds__(256) void bi_gather_kernel(const u16t* __restrict__ SRCb,
                                                        const u16t* __restrict__ DSTb,
                                                        const uint2* __restrict__ bbuck,
                                                        const u32t* __restrict__ boffs,
                                                        const float* __restrict__ nn,
                                                        float* __restrict__ outp){
  int n = blockIdx.x*4 + (threadIdx.x>>6);
  if(n >= NNODE) return;
  int l = threadIdx.x & 63;
  const u32t* Sw = (const u32t*)SRCb;
  const u32t* Dw = (const u32t*)DSTb;
  float2 S = up2(Sw[(size_t)n*64 + l]);
  u32t start = boffs[n], end = boffs[n+1];
  float nmiu = 0.f, nvar = 0.f;
  for(u32t b = start; b < end; b += 64){
    int nb = min(64, (int)(end - b));
    uint2 ent = make_uint2(0u, 0u);               // lanes >= nb: v=0 (harmless)
    if(l < nb){
      u64t ev = __builtin_nontemporal_load((const u64t*)&bbuck[b + l]);
      ent = make_uint2((u32t)ev, (u32t)(ev>>32));
    }
    int nbr = (nb + 3) & ~3;
    for(int j=0;j<nbr;j+=4){
      float2 Dq[4]; float vs[4];
      #pragma unroll
      for(int q=0;q<4;q++){
        u32t b1 = __shfl(ent.x, j+q);
        vs[q]   = __uint_as_float(__shfl((int)ent.y, j+q));
        Dq[q]   = up2(Dw[(size_t)b1*64 + l]);
      }
      #pragma unroll
      for(int q=0;q<4;q++){
        nmiu += vs[q]*(S.x + Dq[q].x);
        nvar += vs[q]*vs[q]*__expf(S.y + Dq[q].y);
      }
    }
  }
  size_t o = (size_t)n*DOUTN + l;
  float nd = __builtin_nontemporal_load(&nn[o]);
  __builtin_nontemporal_store(nd*sqrtf(nvar) + nmiu, &outp[o]);  // exp(0.5*log v)==sqrt(v)
}

extern "C" void kernel_launch(void* const* d_in, const int* in_sizes, int n_in,
                              void* d_out, int out_size, void* d_ws, size_t ws_size,
                              hipStream_t stream){
  const float* X    = (const float*)d_in[0];
  const float* Wg   = (const float*)d_in[1];
  const float* Wm   = (const float*)d_in[2];
  const float* Wsg  = (const float*)d_in[3];
  const float* gv   = (const float*)d_in[4];
  const float* bv   = (const float*)d_in[5];
  const float* nin  = (const float*)d_in[6];
  const float* nout = (const float*)d_in[7];
  const float* nnod = (const float*)d_in[8];
  const int*  gi   = (const int*)d_in[9];
  const int*  ed   = (const int*)d_in[10];
  const int*  be   = (const int*)d_in[11];

  // workspace (76.8 MB):
  //  [0,12.8M)        gbuck uint2          -> phase2: DSTw bf16 [0,25.6M)
  //  [12.8M,38.4M)    xwb bf16             -> (tail of DSTw)
  //  [38.4M,40.0M)    metadata: goffs | gcur | bcur | gpart | bpart | boffs
  //  [40.0M,48.0M)    bbuck uint2 (lives until bi_gather)
  //  [51.2M,76.8M)    hiddenw u32-packed bf16 -> in-place SRCw bf16 after gemm2
  char* ws = (char*)d_ws;
  uint2* gbuck   = (uint2*)ws;
  u16t*  xwb     = (u16t*)(ws + 12800000);
  u32t*  goffs   = (u32t*)(ws + 38400000);
  u32t*  gcur    = (u32t*)(ws + 38800008);
  u32t*  bcur    = (u32t*)(ws + 39200008);
  u32t*  gpart   = (u32t*)(ws + 39600008);
  u32t*  bpart   = (u32t*)(ws + 39601584);
  u32t*  boffs   = (u32t*)(ws + 39603160);
  uint2* bbuck   = (uint2*)(ws + 40003168);
  u32t*  hiddenw = (u32t*)(ws + 51200000);
  u16t*  SRCw    = (u16t*)hiddenw;
  u16t*  DSTw    = (u16t*)ws;

  float* out  = (float*)d_out;
  float* ein  = out + (size_t)NNODE*DOUTN;
  float* eout = ein + (size_t)EDIR*DOUTN;
  // weight-prep arrays in tail of d_out's node region; dead before bi_gather overwrites
  u16t* Wg_pre = (u16t*)((char*)d_out + 25600000 - 131072);
  u16t* Wc_pre = Wg_pre + 32768;

  hipMemsetAsync(gcur, 0, 800000, stream);                      // gcur + bcur
  histAB_kernel   <<<HISTB,   256, 0, stream>>>(gi, be, gcur, bcur);
  scanA_kernel    <<<2*NBLKS, 256, 0, stream>>>(gcur, goffs, gpart, bcur, boffs, bpart);
  scanB_kernel    <<<2,       512, 0, stream>>>(gpart, bpart);
  scanC_kernel    <<<2*NBLKS, 256, 0, stream>>>(goffs, gcur, gpart, boffs, bcur, bpart);
  bucketAB_kernel <<<HISTB,   256, 0, stream>>>(gi, gv, be, bv, gcur, gbuck, bcur, bbuck);
  prep_kernel     <<<256,     256, 0, stream>>>(Wg, Wm, Wsg, Wg_pre, Wc_pre);
  gemm1_kernel    <<<G64,     256, 0, stream>>>(X, Wg_pre, xwb);
  gcn_gather_kernel<<<NNODE/4,256, 0, stream>>>(xwb, gbuck, goffs, hiddenw);
  gemm2_kernel    <<<G64,     256, 0, stream>>>(hiddenw, Wc_pre, DSTw);
  edge_kernel     <<<EDIR/16, 256, 0, stream>>>(SRCw, DSTw, ed, nin, nout, ein, eout);
  bi_gather_kernel<<<NNODE/4, 256, 0, stream>>>(SRCw, DSTw, bbuck, boffs, nnod, out);
}